// Round 4
// baseline (168.880 us; speedup 1.0000x reference)
//
#include <hip/hip_runtime.h>
#include <math.h>

// EdgeAwareLoss — round 4: two balanced kernels, SWAR bodies from r2/r3
// (validated absmax 0.0).
//
// Exactness vs the JAX reference:
//  - img=(t>0.5)*255, integer Sobel => m multiple of 255 => weak==strong,
//    hysteresis while_loop is an immediate fixed point => strong==cand.
//  - units of 255: gx,gy in [-4,4], m=|gx|+|gy|<=6 fits a nibble; SWAR
//    compares ((x|8)-y)&8 exact for values<=7.
//  - direction classes enumerated exactly:
//      horiz: ay==0&&ax>=1 || ay==1&&ax>=3 ; vert: ax==0&&ay>=1 || ax==1&&ay>=3
//  - t in {0,1} => bce=-max(log(t?p:1-p),-100); 1-p exact (Sterbenz / >=0.5).
//
// Round-4 structure (r3: binarize 12us + edge ~40us + finalize 2; ~98us of
// dur_us is fixed harness reset overhead):
//  k1: target(float4, halo) -> binarize -> SWAR sobel(66x5) -> NMS(64x4)
//      -> global strong bits + t bits (2 MB each in d_ws). No barrier fat.
//  k2: strong halo -> 5x5 dilation (u64 shifts) + BCE(pred) -> partials.

typedef unsigned long long u64;
typedef unsigned int u32;
typedef unsigned short u16;

#define NT 256
#define H_IMG 1024
#define W_IMG 1024

constexpr u64 K1 = 0x1111111111111111ULL;
constexpr u64 K7 = 0x7777777777777777ULL;
constexpr u64 K8 = 0x8888888888888888ULL;

__device__ __forceinline__ u64 geq8(u64 x, u64 y) { return ((x | K8) - y) & K8; }
__device__ __forceinline__ u64 gt8(u64 x, u64 y) { return K8 & ~((y | K8) - x); }

// compress u32 nibble-word (low bit of each nibble) -> 8 bits
__device__ __forceinline__ u32 nibc(u32 w) {
    w &= 0x11111111u;
    w = (w | (w >> 3)) & 0x03030303u;
    w = (w | (w >> 6)) & 0x000F000Fu;
    return (w | (w >> 12)) & 0xFFu;
}

// ---------------- kernel 1: binarize + sobel + NMS -> strong/t bits --------
__global__ __launch_bounds__(NT)
void sobel_nms_kernel(const float* __restrict__ target,
                      u64* __restrict__ strongb, u64* __restrict__ tbits)
{
    __shared__ u32 simg[68][12];              // nibbles; col j <-> c0-4+j; words 9..11 zero
    __shared__ u64 mw[66][5];                 // m-row mm <-> global r0-1+mm; nibble k of word wi <-> col c0-3+16wi+k
    __shared__ u64 clw[66][5];                // bit0 horiz, bit1 vert, bit2 sd
    __shared__ __align__(8) u16 sB[64][4];    // strong 16-px masks per tile row

    const int tid = threadIdx.x;
    const int bz = blockIdx.z;
    const int r0 = blockIdx.y * 64;
    const int c0 = blockIdx.x * 64;
    const float* timg = target + (size_t)bz * H_IMG * W_IMG;

    // ---- stage 0: binarize target into nibble LDS (rows r0-2..r0+65) ----
    for (int t = tid; t < 68 * 12; t += NT) {
        int i = t / 12, q = t - i * 12;
        u32 v = 0;
        if (q < 9) {
            int r = r0 - 2 + i; r = r < 0 ? 0 : (r > H_IMG - 1 ? H_IMG - 1 : r);
            const float* rp = timg + (size_t)r * W_IMG;
            int cbase = c0 - 4 + 8 * q;
            if (cbase >= 0 && cbase + 8 <= W_IMG) {
                float4 f0 = *(const float4*)(rp + cbase);
                float4 f1 = *(const float4*)(rp + cbase + 4);
                v  = (f0.x > 0.5f ? 1u : 0u)       | (f0.y > 0.5f ? 1u : 0u) << 4;
                v |= (f0.z > 0.5f ? 1u : 0u) << 8  | (f0.w > 0.5f ? 1u : 0u) << 12;
                v |= (f1.x > 0.5f ? 1u : 0u) << 16 | (f1.y > 0.5f ? 1u : 0u) << 20;
                v |= (f1.z > 0.5f ? 1u : 0u) << 24 | (f1.w > 0.5f ? 1u : 0u) << 28;
            } else {
#pragma unroll
                for (int k = 0; k < 8; ++k) {
                    int c = cbase + k; c = c < 0 ? 0 : (c > W_IMG - 1 ? W_IMG - 1 : c);
                    v |= (rp[c] > 0.5f ? 1u : 0u) << (4 * k);
                }
            }
        }
        simg[i][q] = v;
    }
    __syncthreads();

    // ---- stage A: SWAR sobel -> m + class planes (validated body) ----
    for (int t = tid; t < 66 * 5; t += NT) {
        int mrow = t / 5, wi = t - mrow * 5;
        u64 Lr[3], Cr[3], Rr[3];
#pragma unroll
        for (int k = 0; k < 3; ++k) {
            int ir = mrow + k;
            u32 a0 = simg[ir][2 * wi], a1 = simg[ir][2 * wi + 1], a2 = simg[ir][2 * wi + 2];
            u64 w0 = (u64)a0 | ((u64)a1 << 32);
            Lr[k] = w0;
            Cr[k] = (w0 >> 4) | ((u64)(a2 & 0xFu) << 60);
            Rr[k] = (w0 >> 8) | ((u64)(a2 & 0xFFu) << 56);
        }
        u64 Px = Rr[0] + (Rr[1] << 1) + Rr[2];
        u64 Nx = Lr[0] + (Lr[1] << 1) + Lr[2];
        u64 Py = Lr[2] + (Cr[2] << 1) + Rr[2];
        u64 Ny = Lr[0] + (Cr[0] << 1) + Rr[0];
        u64 Dbx = (Px + K8) - Nx;
        u64 Dby = (Py + K8) - Ny;

        u64 mx = (Dbx >> 3) & K1;
        u64 mfx = (mx << 4) - mx;
        u64 ax = ((Dbx & K7) & mfx) | (((((~Dbx) & K7) + K1)) & ~mfx);
        u64 my = (Dby >> 3) & K1;
        u64 mfy = (my << 4) - my;
        u64 ay = ((Dby & K7) & mfy) | (((((~Dby) & K7) + K1)) & ~mfy);
        u64 m = ax + ay;

        u64 ax0 = ax & K1, ax1b = (ax >> 1) & K1, ax2b = (ax >> 2) & K1;
        u64 ay0 = ay & K1, ay1b = (ay >> 1) & K1, ay2b = (ay >> 2) & K1;
        u64 axnz = ax0 | ax1b | ax2b;
        u64 aynz = ay0 | ay1b | ay2b;
        u64 axe1 = ax0 & ~(ax1b | ax2b);
        u64 aye1 = ay0 & ~(ay1b | ay2b);
        u64 axg3 = ax2b | (ax1b & ax0);
        u64 ayg3 = ay2b | (ay1b & ay0);
        u64 horiz = ((K1 & ~aynz) & axnz) | (aye1 & axg3);
        u64 vert  = ((K1 & ~axnz) & aynz) | (axe1 & ayg3);

        u64 gxp = mx & ((Dbx | (Dbx >> 1) | (Dbx >> 2)) & K1);
        u64 gxn = K1 & ~mx;
        u64 gyp = my & ((Dby | (Dby >> 1) | (Dby >> 2)) & K1);
        u64 gyn = K1 & ~my;
        u64 sd = (gxp & gyn) | (gxn & gyp);

        mw[mrow][wi] = m;
        clw[mrow][wi] = horiz | (vert << 1) | (sd << 2);
    }
    __syncthreads();

    // ---- stage B: NMS for tile pixels only (center nibble = k+3) ----
    for (int t = tid; t < 64 * 4; t += NT) {
        int tr = t >> 2, wb = t & 3;
        u64 a0 = mw[tr][wb],     a1 = mw[tr][wb + 1];
        u64 b0 = mw[tr + 1][wb], b1 = mw[tr + 1][wb + 1];
        u64 g0 = mw[tr + 2][wb], g1 = mw[tr + 2][wb + 1];
        u64 U  = (a0 >> 12) | (a1 << 52);
        u64 UL = (a0 >> 8)  | (a1 << 56);
        u64 UR = (a0 >> 16) | (a1 << 48);
        u64 M  = (b0 >> 12) | (b1 << 52);
        u64 Lf = (b0 >> 8)  | (b1 << 56);
        u64 Rg = (b0 >> 16) | (b1 << 48);
        u64 Dn = (g0 >> 12) | (g1 << 52);
        u64 DL = (g0 >> 8)  | (g1 << 56);
        u64 DR = (g0 >> 16) | (g1 << 48);

        u64 q0 = clw[tr + 1][wb], q1 = clw[tr + 1][wb + 1];
        u64 CC = (q0 >> 12) | (q1 << 52);
        u64 H8 = (CC & K1) << 3;
        u64 V8 = ((CC >> 1) & K1) << 3;
        u64 S8 = ((CC >> 2) & K1) << 3;

        u64 kH = gt8(M, Lf) & geq8(M, Rg);
        u64 kV = gt8(M, U)  & geq8(M, Dn);
        u64 kA = gt8(M, UR) & geq8(M, DL);
        u64 kB = gt8(M, UL) & geq8(M, DR);
        u64 nHV = K8 & ~(H8 | V8);
        u64 keep = (H8 & kH) | (V8 & kV) | (nHV & S8 & kA) | (nHV & ~S8 & kB);
        u64 nz = ((M | (M >> 1) | (M >> 2)) & K1) << 3;   // m >= 1
        u64 cand = keep & nz;

        int rr = r0 + tr;
        if (rr < 1 || rr > H_IMG - 2) cand = 0;

        u64 x = cand >> 3;
        x = (x | (x >> 3))  & 0x0303030303030303ULL;
        x = (x | (x >> 6))  & 0x000F000F000F000FULL;
        x = (x | (x >> 12)) & 0x000000FF000000FFULL;
        x = (x | (x >> 24));
        sB[tr][wb] = (u16)(x & 0xFFFF);
    }
    __syncthreads();

    // ---- stage W: row bitmask writes (strong + t) ----
    if (tid < 64) {
        int tr = tid;
        u64 row = ((const u64*)sB)[tr];
        if (c0 == 0) row &= ~1ULL;                       // col 0 not interior
        if (c0 == W_IMG - 64) row &= ~(1ULL << 63);      // col 1023 not interior
        size_t idx = ((size_t)((bz << 10) | (r0 + tr)) << 4) | (u32)(c0 >> 6);
        strongb[idx] = row;

        const u32* sr = simg[tr + 2];                    // global row r0+tr
        u64 tb = (u64)nibc(sr[0] >> 16);                 // cols c0..c0+3
#pragma unroll
        for (int q = 1; q < 8; ++q)
            tb |= (u64)nibc(sr[q]) << (8 * q - 4);
        tb |= (u64)nibc(sr[8] & 0xFFFFu) << 60;          // cols c0+60..63
        tbits[idx] = tb;
    }
}

// ---------------- kernel 2: 5x5 dilation + weighted BCE -------------------
__global__ __launch_bounds__(NT)
void dilate_bce_kernel(const float* __restrict__ pred,
                       const u64* __restrict__ strongb,
                       const u64* __restrict__ tbits,
                       float* __restrict__ partials)
{
    __shared__ u64 hrow[68];          // horizontal 5-OR, row i <-> global r0-2+i
    __shared__ float wsum[NT / 64];

    const int tid = threadIdx.x;
    const int bz = blockIdx.z;
    const int r0 = blockIdx.y * 64;
    const int c0 = blockIdx.x * 64;
    const int w0 = c0 >> 6;
    const float* pimg = pred + (size_t)bz * H_IMG * W_IMG;

    for (int t = tid; t < 68; t += NT) {
        int r = r0 - 2 + t;
        u64 C = 0, L = 0, R = 0;
        if (r >= 0 && r < H_IMG) {
            size_t base = (size_t)((bz << 10) | r) << 4;
            C = strongb[base + w0];
            L = (w0 > 0)  ? strongb[base + w0 - 1] : 0;
            R = (w0 < 15) ? strongb[base + w0 + 1] : 0;
        }
        u64 h = C;
        h |= (C >> 1) | (R << 63);
        h |= (C >> 2) | (R << 62);
        h |= (C << 1) | (L >> 63);
        h |= (C << 2) | (L >> 62);
        hrow[t] = h;
    }
    __syncthreads();

    float accv = 0.0f;
    {
        int tr = tid >> 2, q = tid & 3;
        u64 ez = hrow[tr] | hrow[tr + 1] | hrow[tr + 2] | hrow[tr + 3] | hrow[tr + 4];
        u32 ezw = (u32)(ez >> (16 * q));
        u64 tword = tbits[((size_t)((bz << 10) | (r0 + tr)) << 4) | (u32)w0];
        u32 t16 = (u32)(tword >> (16 * q));
        const float4* pv4 = (const float4*)(pimg + (size_t)(r0 + tr) * W_IMG + (c0 + 16 * q));
#pragma unroll
        for (int kk = 0; kk < 4; ++kk) {
            float4 pv = pv4[kk];
            float ps[4] = {pv.x, pv.y, pv.z, pv.w};
#pragma unroll
            for (int cc = 0; cc < 4; ++cc) {
                int k = kk * 4 + cc;
                float p = ps[cc];
                float xx = ((t16 >> k) & 1) ? p : 1.0f - p;
                float lg = fmaxf(__logf(xx), -100.0f);
                float w = ((ezw >> k) & 1) ? 5.0f : 1.0f;
                accv = fmaf(w, -lg, accv);
            }
        }
    }

    for (int off = 32; off > 0; off >>= 1)
        accv += __shfl_down(accv, off);
    int wid = tid >> 6, lane = tid & 63;
    if (lane == 0) wsum[wid] = accv;
    __syncthreads();
    if (tid == 0) {
        int bi = (blockIdx.z * gridDim.y + blockIdx.y) * gridDim.x + blockIdx.x;
        partials[bi] = wsum[0] + wsum[1] + wsum[2] + wsum[3];
    }
}

__global__ __launch_bounds__(256)
void finalize_kernel(const float* __restrict__ partials, float* __restrict__ out,
                     int nblocks, double invN)
{
    __shared__ double ws[4];
    double s = 0.0;
    for (int i = threadIdx.x; i < nblocks; i += 256) s += (double)partials[i];
    for (int off = 32; off > 0; off >>= 1) s += __shfl_down(s, off);
    int wid = threadIdx.x >> 6, lane = threadIdx.x & 63;
    if (lane == 0) ws[wid] = s;
    __syncthreads();
    if (threadIdx.x == 0) out[0] = (float)((ws[0] + ws[1] + ws[2] + ws[3]) * invN);
}

extern "C" void kernel_launch(void* const* d_in, const int* in_sizes, int n_in,
                              void* d_out, int out_size, void* d_ws, size_t ws_size,
                              hipStream_t stream)
{
    (void)n_in; (void)out_size; (void)ws_size;
    const float* pred   = (const float*)d_in[0];
    const float* target = (const float*)d_in[1];
    const int N = in_sizes[0];
    const int B = N / (H_IMG * W_IMG);

    // ws: [0,16K) partials; [16K, 16K+2M) strong bits; [16K+2M, 16K+4M) t bits
    float* partials = (float*)d_ws;
    u64* strongb = (u64*)((char*)d_ws + (16 << 10));
    u64* tbits   = (u64*)((char*)d_ws + (16 << 10) + ((size_t)B << 21));

    dim3 grid(W_IMG / 64, H_IMG / 64, B);
    int nblocks = (W_IMG / 64) * (H_IMG / 64) * B;

    sobel_nms_kernel<<<grid, NT, 0, stream>>>(target, strongb, tbits);
    dilate_bce_kernel<<<grid, NT, 0, stream>>>(pred, strongb, tbits, partials);
    finalize_kernel<<<1, 256, 0, stream>>>(partials, (float*)d_out, nblocks,
                                           1.0 / (double)N);
}

// Round 5
// 155.764 us; speedup vs baseline: 1.0842x; 1.0842x over previous
//
#include <hip/hip_runtime.h>
#include <math.h>

// EdgeAwareLoss — round 5: r3 monolith topology (r4's 2-kernel split regressed:
// uncoalesced 128B-stride bitmask I/O + extra dependent launch), with staging
// moved into the binarize pre-pass (nibble-format Gp array) so the edge kernel
// has no stage-0 and reads its Sobel windows / t-bits straight from L2.
//
// Exactness vs the JAX reference (validated absmax 0.0 in r1-r4):
//  - img=(t>0.5)*255, integer Sobel => m multiple of 255 => weak==strong,
//    hysteresis while_loop is an immediate fixed point => strong==cand.
//  - units of 255: gx,gy in [-4,4], m=|gx|+|gy|<=6 fits a nibble; SWAR
//    compares ((x|8)-y)&8 exact for values<=7.
//  - direction classes enumerated exactly:
//      horiz: ay==0&&ax>=1 || ay==1&&ax>=3 ; vert: ax==0&&ay>=1 || ax==1&&ay>=3
//  - t in {0,1} => bce=-max(log(t?p:1-p),-100); 1-p exact (Sterbenz / >=0.5).
//
// Gp layout: per (image,row), 132 u32 words; word w (1..131) = nibbles of
// cols 8w-12 .. 8w-5, col-clamped to [0,1023]. Every 64-col tile window
// (c0-4 .. ) starts at col ≡ 4 (mod 8) => always word-aligned in Gp.
// Word 0 never written/read.

typedef unsigned long long u64;
typedef unsigned int u32;
typedef unsigned short u16;

#define NT 256
#define H_IMG 1024
#define W_IMG 1024
#define GPW 132                 // Gp words per row

constexpr u64 K1 = 0x1111111111111111ULL;
constexpr u64 K7 = 0x7777777777777777ULL;
constexpr u64 K8 = 0x8888888888888888ULL;

__device__ __forceinline__ u64 geq8(u64 x, u64 y) { return ((x | K8) - y) & K8; }
__device__ __forceinline__ u64 gt8(u64 x, u64 y) { return K8 & ~((y | K8) - x); }

// ---- pre-pass: binarize target into nibble words (with col-clamped pads) ----
__global__ __launch_bounds__(256)
void binarize_kernel(const float* __restrict__ target, u32* __restrict__ Gp,
                     int ntasks)
{
    int t = blockIdx.x * 256 + threadIdx.x;
    if (t >= ntasks) return;
    int w = t % 131 + 1;                  // 1..131
    int rlin = t / 131;                   // bz*1024 + r
    const float* rp = target + (size_t)rlin * W_IMG;
    int cb = 8 * w - 12;
    u32 v;
    if (w >= 2 && w <= 128) {             // fully interior: cb in [4,1012]
        float4 f0 = *(const float4*)(rp + cb);
        float4 f1 = *(const float4*)(rp + cb + 4);
        v  = (f0.x > 0.5f ? 1u : 0u)        | (f0.y > 0.5f ? 1u : 0u) << 4;
        v |= (f0.z > 0.5f ? 1u : 0u) << 8   | (f0.w > 0.5f ? 1u : 0u) << 12;
        v |= (f1.x > 0.5f ? 1u : 0u) << 16  | (f1.y > 0.5f ? 1u : 0u) << 20;
        v |= (f1.z > 0.5f ? 1u : 0u) << 24  | (f1.w > 0.5f ? 1u : 0u) << 28;
    } else {                              // clamped boundary words
        v = 0;
#pragma unroll
        for (int k = 0; k < 8; ++k) {
            int c = cb + k; c = c < 0 ? 0 : (c > W_IMG - 1 ? W_IMG - 1 : c);
            v |= (rp[c] > 0.5f ? 1u : 0u) << (4 * k);
        }
    }
    Gp[(size_t)rlin * GPW + w] = v;
}

// ---------------- main kernel: sobel + NMS + dilate + BCE -----------------
__global__ __launch_bounds__(NT)
void edge_loss_kernel(const float* __restrict__ pred,
                      const u32* __restrict__ Gp,
                      float* __restrict__ partials)
{
    __shared__ u64 mw[70][6];      // m nibbles; nibble k of word wi <-> col c0-3+16wi+k; word5=0
    __shared__ u64 clw[70][6];     // bit0 horiz, bit1 vert, bit2 sd
    __shared__ u16 ssw[68][5];     // strong 16-px masks, s-col j <-> tile col j-2
    __shared__ u64 hrow[68];       // horizontal 5-OR row masks (bit j = tile col j)
    __shared__ float wsum[NT / 64];

    const int tid = threadIdx.x;
    const int bz = blockIdx.z;
    const int r0 = blockIdx.y * 64;
    const int c0 = blockIdx.x * 64;
    const float* pimg = pred + (size_t)bz * H_IMG * W_IMG;
    const u32* gb = Gp + (size_t)(bz << 10) * GPW;
    const int wbase = (c0 >> 3) + 1;     // Gp word of cols c0-4..c0+3

    // ---- Stage A: SWAR sobel from Gp -> m + class planes ----
    for (int t = tid; t < 70 * 6; t += NT) {
        int mrow = t / 6, wi = t - mrow * 6;
        if (wi == 5) { mw[mrow][5] = 0; clw[mrow][5] = 0; continue; }
        u64 Lr[3], Cr[3], Rr[3];
#pragma unroll
        for (int k = 0; k < 3; ++k) {
            int r = r0 - 4 + mrow + k;
            r = r < 0 ? 0 : (r > H_IMG - 1 ? H_IMG - 1 : r);
            const u32* rw = gb + (size_t)r * GPW + (wbase + 2 * wi);
            u32 a0 = rw[0], a1 = rw[1], a2 = rw[2];
            u64 w0 = (u64)a0 | ((u64)a1 << 32);
            Lr[k] = w0;                                        // col-1
            Cr[k] = (w0 >> 4) | ((u64)(a2 & 0xFu) << 60);      // center
            Rr[k] = (w0 >> 8) | ((u64)(a2 & 0xFFu) << 56);     // col+1
        }
        u64 Px = Rr[0] + (Rr[1] << 1) + Rr[2];
        u64 Nx = Lr[0] + (Lr[1] << 1) + Lr[2];
        u64 Py = Lr[2] + (Cr[2] << 1) + Rr[2];
        u64 Ny = Lr[0] + (Cr[0] << 1) + Rr[0];
        u64 Dbx = (Px + K8) - Nx;                // gx+8 per nibble, no borrows
        u64 Dby = (Py + K8) - Ny;

        u64 mx = (Dbx >> 3) & K1;                // gx >= 0
        u64 mfx = (mx << 4) - mx;
        u64 ax = ((Dbx & K7) & mfx) | (((((~Dbx) & K7) + K1)) & ~mfx);
        u64 my = (Dby >> 3) & K1;
        u64 mfy = (my << 4) - my;
        u64 ay = ((Dby & K7) & mfy) | (((((~Dby) & K7) + K1)) & ~mfy);
        u64 m = ax + ay;                         // <= 6

        u64 ax0 = ax & K1, ax1b = (ax >> 1) & K1, ax2b = (ax >> 2) & K1;
        u64 ay0 = ay & K1, ay1b = (ay >> 1) & K1, ay2b = (ay >> 2) & K1;
        u64 axnz = ax0 | ax1b | ax2b;
        u64 aynz = ay0 | ay1b | ay2b;
        u64 axe1 = ax0 & ~(ax1b | ax2b);
        u64 aye1 = ay0 & ~(ay1b | ay2b);
        u64 axg3 = ax2b | (ax1b & ax0);
        u64 ayg3 = ay2b | (ay1b & ay0);
        u64 horiz = ((K1 & ~aynz) & axnz) | (aye1 & axg3);
        u64 vert  = ((K1 & ~axnz) & aynz) | (axe1 & ayg3);

        u64 gxp = mx & axnz;                     // gx > 0  (reuse: ax!=0)
        u64 gxn = K1 & ~mx;                      // gx < 0
        u64 gyp = my & aynz;
        u64 gyn = K1 & ~my;
        u64 sd = (gxp & gyn) | (gxn & gyp);

        mw[mrow][wi] = m;
        clw[mrow][wi] = horiz | (vert << 1) | (sd << 2);
    }
    __syncthreads();

    // ---- Stage B: SWAR NMS + threshold + interior -> strong bitmasks ----
    for (int t = tid; t < 68 * 5; t += NT) {
        int srow = t / 5, wi = t - srow * 5;
        u16 outm = 0;
        int rr = r0 - 2 + srow;
        if (rr >= 1 && rr <= H_IMG - 2) {
            int ra = srow, rb = srow + 1, rc = srow + 2;
            u64 a0 = mw[ra][wi], a1 = mw[ra][wi + 1];
            u64 b0 = mw[rb][wi], b1 = mw[rb][wi + 1];
            u64 g0 = mw[rc][wi], g1 = mw[rc][wi + 1];
            u64 U  = (a0 >> 4) | (a1 << 60);
            u64 UL = a0;
            u64 UR = (a0 >> 8) | (a1 << 56);
            u64 M  = (b0 >> 4) | (b1 << 60);
            u64 Lf = b0;
            u64 Rg = (b0 >> 8) | (b1 << 56);
            u64 Dn = (g0 >> 4) | (g1 << 60);
            u64 DL = g0;
            u64 DR = (g0 >> 8) | (g1 << 56);

            u64 q0 = clw[rb][wi], q1 = clw[rb][wi + 1];
            u64 CC = (q0 >> 4) | (q1 << 60);
            u64 H8 = (CC & K1) << 3;
            u64 V8 = ((CC >> 1) & K1) << 3;
            u64 S8 = ((CC >> 2) & K1) << 3;

            u64 kH = gt8(M, Lf) & geq8(M, Rg);
            u64 kV = gt8(M, U)  & geq8(M, Dn);
            u64 kA = gt8(M, UR) & geq8(M, DL);
            u64 kB = gt8(M, UL) & geq8(M, DR);
            u64 nHV = K8 & ~(H8 | V8);
            u64 keep = (H8 & kH) | (V8 & kV) | (nHV & S8 & kA) | (nHV & ~S8 & kB);
            u64 nz = ((M | (M >> 1) | (M >> 2)) & K1) << 3;   // m >= 1
            u64 cand = keep & nz;

            int basec = c0 - 2 + 16 * wi;
            int lo = 1 - basec; if (lo < 0) lo = 0;
            int hi = (W_IMG - 2) - basec; if (hi > 15) hi = 15;
            if (lo > hi) cand = 0;
            else cand &= (~0ULL >> ((15 - hi) * 4)) & (~0ULL << (lo * 4));

            u64 x = cand >> 3;
            x = (x | (x >> 3))  & 0x0303030303030303ULL;
            x = (x | (x >> 6))  & 0x000F000F000F000FULL;
            x = (x | (x >> 12)) & 0x000000FF000000FFULL;
            x = (x | (x >> 24));
            outm = (u16)(x & 0xFFFF);
        }
        ssw[srow][wi] = outm;
    }
    __syncthreads();

    // ---- Stage C: horizontal 5-OR over strong row bitmasks ----
    for (int t = tid; t < 68; t += NT) {
        u64 lo = (u64)ssw[t][0] | ((u64)ssw[t][1] << 16) |
                 ((u64)ssw[t][2] << 32) | ((u64)ssw[t][3] << 48);
        u64 hib = (u64)(ssw[t][4] & 0xFu);
        u64 acc = lo;
#pragma unroll
        for (int d = 1; d <= 4; ++d)
            acc |= (lo >> d) | (hib << (64 - d));
        hrow[t] = acc;
    }
    __syncthreads();

    // ---- Stage D: vertical 5-OR + weighted BCE; 16 px / thread ----
    float accv = 0.0f;
    {
        int tr = tid >> 2, q = tid & 3;
        u64 ez = hrow[tr] | hrow[tr + 1] | hrow[tr + 2] | hrow[tr + 3] | hrow[tr + 4];
        u32 ezw = (u32)(ez >> (16 * q));
        // t nibbles for cols c0+16q .. +15, from Gp (L2-hot)
        const u32* rw = gb + (size_t)(r0 + tr) * GPW + ((c0 >> 3) + 2 * q + 1);
        u32 g0 = rw[0], g1 = rw[1], g2 = rw[2];
        u64 nb = ((u64)(g0 >> 16)) | ((u64)g1 << 16) | (((u64)(g2 & 0xFFFFu)) << 48);
        const float4* pv4 = (const float4*)(pimg + (size_t)(r0 + tr) * W_IMG + (c0 + 16 * q));
#pragma unroll
        for (int kk = 0; kk < 4; ++kk) {
            float4 pv = pv4[kk];
            float ps[4] = {pv.x, pv.y, pv.z, pv.w};
#pragma unroll
            for (int cc = 0; cc < 4; ++cc) {
                int k = kk * 4 + cc;
                float p = ps[cc];
                float xx = ((nb >> (4 * k)) & 1) ? p : 1.0f - p;
                float lg = fmaxf(__logf(xx), -100.0f);
                float w = ((ezw >> k) & 1) ? 5.0f : 1.0f;
                accv = fmaf(w, -lg, accv);
            }
        }
    }

    for (int off = 32; off > 0; off >>= 1)
        accv += __shfl_down(accv, off);
    int wid = tid >> 6, lane = tid & 63;
    if (lane == 0) wsum[wid] = accv;
    __syncthreads();
    if (tid == 0) {
        int bi = (blockIdx.z * gridDim.y + blockIdx.y) * gridDim.x + blockIdx.x;
        partials[bi] = wsum[0] + wsum[1] + wsum[2] + wsum[3];
    }
}

__global__ __launch_bounds__(256)
void finalize_kernel(const float* __restrict__ partials, float* __restrict__ out,
                     int nblocks, double invN)
{
    __shared__ double ws[4];
    double s = 0.0;
    for (int i = threadIdx.x; i < nblocks; i += 256) s += (double)partials[i];
    for (int off = 32; off > 0; off >>= 1) s += __shfl_down(s, off);
    int wid = threadIdx.x >> 6, lane = threadIdx.x & 63;
    if (lane == 0) ws[wid] = s;
    __syncthreads();
    if (threadIdx.x == 0) out[0] = (float)((ws[0] + ws[1] + ws[2] + ws[3]) * invN);
}

extern "C" void kernel_launch(void* const* d_in, const int* in_sizes, int n_in,
                              void* d_out, int out_size, void* d_ws, size_t ws_size,
                              hipStream_t stream)
{
    (void)n_in; (void)out_size; (void)ws_size;
    const float* pred   = (const float*)d_in[0];
    const float* target = (const float*)d_in[1];
    const int N = in_sizes[0];
    const int B = N / (H_IMG * W_IMG);

    // ws: [0,16K) per-block partials; [16K, ...) Gp nibble array (B*1024*132 u32)
    float* partials = (float*)d_ws;
    u32* Gp = (u32*)((char*)d_ws + (16 << 10));

    const int ntasks = B * H_IMG * 131;
    binarize_kernel<<<(ntasks + 255) / 256, 256, 0, stream>>>(target, Gp, ntasks);

    dim3 grid(W_IMG / 64, H_IMG / 64, B);
    int nblocks = (W_IMG / 64) * (H_IMG / 64) * B;
    edge_loss_kernel<<<grid, NT, 0, stream>>>(pred, Gp, partials);
    finalize_kernel<<<1, 256, 0, stream>>>(partials, (float*)d_out, nblocks,
                                           1.0 / (double)N);
}

// Round 6
// 153.549 us; speedup vs baseline: 1.0998x; 1.0144x over previous
//
#include <hip/hip_runtime.h>
#include <math.h>

// EdgeAwareLoss — round 6: single-pass rolling-row kernel.
// One wave = one full 1024-px image row (64 lanes x 16 nibble-px). Each wave
// marches down an 8-row band keeping rolling register windows:
//   img rows {s-2,s-1,s} (+L/R shifted via __shfl) -> separable SWAR Sobel
//   m rows {s-3,s-2,s-1} (+L/R)                    -> SWAR NMS -> strong row
//   h rows {s-6..s-2} (horizontal 5-OR bitmasks)   -> vertical 5-OR = edge zone
//   t 5-deep delay line                            -> BCE weight/target
// No LDS, no barriers, no pre-pass, no intermediate global arrays (r4/r5
// lesson: global round-trips of intermediates lose). Horizontal halos via
// lane shuffles; vertical halos are the 8 warm-up rows per band.
//
// Exactness vs the JAX reference (SWAR bodies validated absmax 0.0 in r1-r5):
//  - img=(t>0.5)*255, integer Sobel => m multiple of 255 => weak==strong,
//    hysteresis while_loop is an immediate fixed point => strong==cand.
//  - units of 255: gx,gy in [-4,4], m=|gx|+|gy|<=6 fits a nibble; SWAR
//    compares ((x|8)-y)&8 exact for values<=7.
//  - separable Sobel: Px=R(row-1)+2R(row)+R(row+1) etc — same integer sums.
//  - direction classes enumerated exactly:
//      horiz: ay==0&&ax>=1 || ay==1&&ax>=3 ; vert: ax==0&&ay>=1 || ax==1&&ay>=3
//  - row/col edge-replicate clamp == conv 'edge' pad; NMS/dilation boundary
//    values masked by interior test / zero-padded shuffles.
//  - t in {0,1} => bce=-max(log(t?p:1-p),-100); 1-p exact (Sterbenz / >=0.5).

typedef unsigned long long u64;
typedef unsigned int u32;

#define H_IMG 1024
#define W_IMG 1024
#define BH 8                     // rows emitted per band (wave)

constexpr u64 K1 = 0x1111111111111111ULL;
constexpr u64 K7 = 0x7777777777777777ULL;
constexpr u64 K8 = 0x8888888888888888ULL;

__device__ __forceinline__ u64 geq8(u64 x, u64 y) { return ((x | K8) - y) & K8; }
__device__ __forceinline__ u64 gt8(u64 x, u64 y) { return K8 & ~((y | K8) - x); }

// bits at positions 4k (16 of them) -> dense 16-bit mask
__device__ __forceinline__ u32 foldK1(u64 x) {
    x = (x | (x >> 3))  & 0x0303030303030303ULL;
    x = (x | (x >> 6))  & 0x000F000F000F000FULL;
    x = (x | (x >> 12)) & 0x000000FF000000FFULL;
    x = (x | (x >> 24));
    return (u32)x & 0xFFFFu;
}

__global__ __launch_bounds__(256)
void edge_loss_kernel(const float* __restrict__ pred,
                      const float* __restrict__ target,
                      float* __restrict__ partials)
{
    const int tid  = threadIdx.x;
    const int lane = tid & 63;
    const int band = blockIdx.x * 4 + (tid >> 6);   // 4 waves/block, adjacent bands
    const int img  = band >> 7;                      // 128 bands per image
    const int a    = (band & 127) * BH;              // first emitted row
    const float* timg = target + ((size_t)img << 20);
    const float* pimg = pred   + ((size_t)img << 20);
    const int cb = lane * 16;                        // this lane's first col

    // rolling state (init 0; warm-up garbage rotates out before emission)
    u64 iw0 = 0, iw1 = 0, iw2 = 0;                   // img rows s-2,s-1,s
    u64 iL0 = 0, iL1 = 0, iL2 = 0;                   // col-1 shifted
    u64 iR0 = 0, iR1 = 0, iR2 = 0;                   // col+1 shifted
    u64 m0 = 0, m1 = 0, m2 = 0;                      // m rows s-3,s-2,s-1
    u64 mL0 = 0, mL1 = 0, mL2 = 0, mR0 = 0, mR1 = 0, mR2 = 0;
    u64 cl0 = 0, cl1 = 0;                            // class rows s-2,s-1
    u32 h0 = 0, h1 = 0, h2 = 0, h3 = 0, h4 = 0;      // h rows s-6..s-2
    u32 tq0 = 0, tq1 = 0, tq2 = 0, tq3 = 0, tq4 = 0; // t-bit rows s..s-4
    float accv = 0.0f;

    auto step = [&](int s) {
        // ---- ingest img row s (row clamp == 'edge' pad) ----
        iw0 = iw1; iw1 = iw2; iL0 = iL1; iL1 = iL2; iR0 = iR1; iR1 = iR2;
        int rc = s < 0 ? 0 : (s > H_IMG - 1 ? H_IMG - 1 : s);
        const float4* tp = (const float4*)(timg + (size_t)rc * W_IMG + cb);
        float4 f0 = tp[0], f1 = tp[1], f2 = tp[2], f3 = tp[3];
        u64 w = 0;
        w |= (u64)(f0.x > 0.5f) << 0  | (u64)(f0.y > 0.5f) << 4;
        w |= (u64)(f0.z > 0.5f) << 8  | (u64)(f0.w > 0.5f) << 12;
        w |= (u64)(f1.x > 0.5f) << 16 | (u64)(f1.y > 0.5f) << 20;
        w |= (u64)(f1.z > 0.5f) << 24 | (u64)(f1.w > 0.5f) << 28;
        w |= (u64)(f2.x > 0.5f) << 32 | (u64)(f2.y > 0.5f) << 36;
        w |= (u64)(f2.z > 0.5f) << 40 | (u64)(f2.w > 0.5f) << 44;
        w |= (u64)(f3.x > 0.5f) << 48 | (u64)(f3.y > 0.5f) << 52;
        w |= (u64)(f3.z > 0.5f) << 56 | (u64)(f3.w > 0.5f) << 60;
        iw2 = w;
        u64 up = __shfl_up(w, 1);
        u64 dn = __shfl_down(w, 1);
        if (lane == 0)  up = w << 60;                // col -1 := col 0 (clamp)
        if (lane == 63) dn = w >> 60;                // col 1024 := col 1023
        iL2 = (w << 4) | (up >> 60);
        iR2 = (w >> 4) | ((dn & 0xFULL) << 60);
        tq4 = tq3; tq3 = tq2; tq2 = tq1; tq1 = tq0;
        tq0 = foldK1(w & K1);

        // ---- separable SWAR Sobel -> m/class row s-1 (validated body) ----
        u64 Px = iR0 + (iR1 << 1) + iR2;
        u64 Nx = iL0 + (iL1 << 1) + iL2;
        u64 Py = iL2 + (iw2 << 1) + iR2;
        u64 Ny = iL0 + (iw0 << 1) + iR0;
        u64 Dbx = (Px + K8) - Nx;                    // gx+8 per nibble
        u64 Dby = (Py + K8) - Ny;
        u64 mxp = (Dbx >> 3) & K1;                   // gx >= 0
        u64 mfx = (mxp << 4) - mxp;
        u64 ax = ((Dbx & K7) & mfx) | ((((~Dbx) & K7) + K1) & ~mfx);
        u64 myp = (Dby >> 3) & K1;
        u64 mfy = (myp << 4) - myp;
        u64 ay = ((Dby & K7) & mfy) | ((((~Dby) & K7) + K1) & ~mfy);
        u64 mNew = ax + ay;                          // <= 6
        u64 ax0 = ax & K1, ax1b = (ax >> 1) & K1, ax2b = (ax >> 2) & K1;
        u64 ay0 = ay & K1, ay1b = (ay >> 1) & K1, ay2b = (ay >> 2) & K1;
        u64 axnz = ax0 | ax1b | ax2b;
        u64 aynz = ay0 | ay1b | ay2b;
        u64 axe1 = ax0 & ~(ax1b | ax2b);
        u64 aye1 = ay0 & ~(ay1b | ay2b);
        u64 axg3 = ax2b | (ax1b & ax0);
        u64 ayg3 = ay2b | (ay1b & ay0);
        u64 horiz = ((K1 & ~aynz) & axnz) | (aye1 & axg3);
        u64 vert  = ((K1 & ~axnz) & aynz) | (axe1 & ayg3);
        u64 sd = ((mxp & axnz) & (K1 & ~myp)) | ((K1 & ~mxp) & (myp & aynz));

        m0 = m1; m1 = m2; mL0 = mL1; mL1 = mL2; mR0 = mR1; mR1 = mR2;
        cl0 = cl1; cl1 = horiz | (vert << 1) | (sd << 2);
        u64 upm = __shfl_up(mNew, 1);
        u64 dnm = __shfl_down(mNew, 1);
        m2 = mNew;
        mL2 = (mNew << 4) | (upm >> 60);             // boundary nibbles masked later
        mR2 = (mNew >> 4) | ((dnm & 0xFULL) << 60);

        // ---- SWAR NMS row s-2 (validated body; operands center-aligned) ----
        u64 CC = cl0;
        u64 H8 = (CC & K1) << 3;
        u64 V8 = ((CC >> 1) & K1) << 3;
        u64 S8 = ((CC >> 2) & K1) << 3;
        u64 kH = gt8(m1, mL1) & geq8(m1, mR1);       // left / right
        u64 kV = gt8(m1, m0)  & geq8(m1, m2);        // up / down
        u64 kA = gt8(m1, mR0) & geq8(m1, mL2);       // UR / DL (sign_diff)
        u64 kB = gt8(m1, mL0) & geq8(m1, mR2);       // UL / DR
        u64 nHV = K8 & ~(H8 | V8);
        u64 keep = (H8 & kH) | (V8 & kV) | (nHV & S8 & kA) | (nHV & ~S8 & kB);
        u64 nz = ((m1 | (m1 >> 1) | (m1 >> 2)) & K1) << 3;   // m >= 1
        u64 cand = keep & nz;
        int rr = s - 2;
        if (rr < 1 || rr > H_IMG - 2) cand = 0;      // row interior (uniform)
        if (lane == 0)  cand &= ~0xFULL;             // col 0 not interior
        if (lane == 63) cand &= ~(0xFULL << 60);     // col 1023 not interior
        u32 sNew = foldK1((cand >> 3) & K1);

        // ---- horizontal 5-OR (zero-padded at image edges) ----
        u32 hu = __shfl_up(sNew, 1);
        u32 hd = __shfl_down(sNew, 1);
        if (lane == 0)  hu = 0;
        if (lane == 63) hd = 0;
        u32 hNew = sNew
                 | ((sNew >> 1) | ((hd & 1u) << 15))
                 | ((sNew >> 2) | ((hd & 3u) << 14))
                 | (((sNew << 1) & 0xFFFFu) | (hu >> 15))
                 | (((sNew << 2) & 0xFFFFu) | (hu >> 14));
        h0 = h1; h1 = h2; h2 = h3; h3 = h4; h4 = hNew;
    };

    // warm-up: prime histories (outputs rotate out before emission)
    for (int s = a - 4; s < a + 4; ++s) step(s);
    // main: emit BCE for row s-4
    for (int s = a + 4; s < a + 4 + BH; ++s) {
        step(s);
        int r = s - 4;
        u32 ez = h0 | h1 | h2 | h3 | h4;             // rows r-2..r+2
        u32 tb = tq4;                                // t bits of row r
        const float4* pp = (const float4*)(pimg + (size_t)r * W_IMG + cb);
#pragma unroll
        for (int kk = 0; kk < 4; ++kk) {
            float4 pv = pp[kk];
            float ps[4] = {pv.x, pv.y, pv.z, pv.w};
#pragma unroll
            for (int cc = 0; cc < 4; ++cc) {
                int k = kk * 4 + cc;
                float p = ps[cc];
                float xx = ((tb >> k) & 1) ? p : 1.0f - p;
                float lg = fmaxf(__logf(xx), -100.0f);
                accv = fmaf(((ez >> k) & 1) ? 5.0f : 1.0f, -lg, accv);
            }
        }
    }

    // wave reduction -> one partial per band (deterministic, atomic-free)
    for (int off = 32; off > 0; off >>= 1)
        accv += __shfl_down(accv, off);
    if (lane == 0) partials[band] = accv;
}

__global__ __launch_bounds__(256)
void finalize_kernel(const float* __restrict__ partials, float* __restrict__ out,
                     int nbands, double invN)
{
    __shared__ double ws[4];
    double s = 0.0;
    for (int i = threadIdx.x; i < nbands; i += 256) s += (double)partials[i];
    for (int off = 32; off > 0; off >>= 1) s += __shfl_down(s, off);
    int wid = threadIdx.x >> 6, lane = threadIdx.x & 63;
    if (lane == 0) ws[wid] = s;
    __syncthreads();
    if (threadIdx.x == 0) out[0] = (float)((ws[0] + ws[1] + ws[2] + ws[3]) * invN);
}

extern "C" void kernel_launch(void* const* d_in, const int* in_sizes, int n_in,
                              void* d_out, int out_size, void* d_ws, size_t ws_size,
                              hipStream_t stream)
{
    (void)n_in; (void)out_size; (void)ws_size;
    const float* pred   = (const float*)d_in[0];
    const float* target = (const float*)d_in[1];
    const int N = in_sizes[0];
    const int B = N >> 20;                            // images (16)

    float* partials = (float*)d_ws;                   // nbands floats, all rewritten
    const int nbands = B * (H_IMG / BH);              // 2048
    const int nblocks = nbands / 4;                   // 4 bands (waves) per block

    edge_loss_kernel<<<nblocks, 256, 0, stream>>>(pred, target, partials);
    finalize_kernel<<<1, 256, 0, stream>>>(partials, (float*)d_out, nbands,
                                           1.0 / (double)N);
}

// Round 7
// 153.129 us; speedup vs baseline: 1.1029x; 1.0027x over previous
//
#include <hip/hip_runtime.h>
#include <math.h>

// EdgeAwareLoss — round 7: r6 rolling-row kernel + depth-1 software pipelining.
// r6 post-mortem: VALUBusy 43%, occ 18% — loads consumed ~10 instrs after
// issue; ~900-cyc HBM latency exposed with only 2 waves/SIMD. Fix: at step s,
// prefetch target row s+1 and pred row s-3; consume the PREVIOUS step's
// registers. All SWAR bodies identical to r6 (absmax 0.0 in rounds 1-6).
//
// Exactness vs the JAX reference:
//  - img=(t>0.5)*255, integer Sobel => m multiple of 255 => weak==strong,
//    hysteresis while_loop is an immediate fixed point => strong==cand.
//  - units of 255: gx,gy in [-4,4], m=|gx|+|gy|<=6 fits a nibble; SWAR
//    compares ((x|8)-y)&8 exact for values<=7.
//  - separable Sobel: Px=R(row-1)+2R(row)+R(row+1) etc — same integer sums.
//  - direction classes enumerated exactly:
//      horiz: ay==0&&ax>=1 || ay==1&&ax>=3 ; vert: ax==0&&ay>=1 || ax==1&&ay>=3
//  - row/col edge-replicate clamp == conv 'edge' pad; boundary masked by
//    interior test / zero-padded shuffles.
//  - t in {0,1} => bce=-max(log(t?p:1-p),-100); 1-p exact (Sterbenz / >=0.5).

typedef unsigned long long u64;
typedef unsigned int u32;

#define H_IMG 1024
#define W_IMG 1024
#define BH 8                     // rows emitted per band (wave)

constexpr u64 K1 = 0x1111111111111111ULL;
constexpr u64 K7 = 0x7777777777777777ULL;
constexpr u64 K8 = 0x8888888888888888ULL;

__device__ __forceinline__ u64 geq8(u64 x, u64 y) { return ((x | K8) - y) & K8; }
__device__ __forceinline__ u64 gt8(u64 x, u64 y) { return K8 & ~((y | K8) - x); }

// bits at positions 4k (16 of them) -> dense 16-bit mask
__device__ __forceinline__ u32 foldK1(u64 x) {
    x = (x | (x >> 3))  & 0x0303030303030303ULL;
    x = (x | (x >> 6))  & 0x000F000F000F000FULL;
    x = (x | (x >> 12)) & 0x000000FF000000FFULL;
    x = (x | (x >> 24));
    return (u32)x & 0xFFFFu;
}

__global__ __launch_bounds__(256)
void edge_loss_kernel(const float* __restrict__ pred,
                      const float* __restrict__ target,
                      float* __restrict__ partials)
{
    const int tid  = threadIdx.x;
    const int lane = tid & 63;
    const int band = blockIdx.x * 4 + (tid >> 6);   // 4 waves/block, adjacent bands
    const int img  = band >> 7;                      // 128 bands per image
    const int a    = (band & 127) * BH;              // first emitted row
    const float* timg = target + ((size_t)img << 20);
    const float* pimg = pred   + ((size_t)img << 20);
    const int cb = lane * 16;                        // this lane's first col

    // rolling state
    u64 iw0 = 0, iw1 = 0, iw2 = 0;                   // img rows s-2,s-1,s
    u64 iL0 = 0, iL1 = 0, iL2 = 0;
    u64 iR0 = 0, iR1 = 0, iR2 = 0;
    u64 m0 = 0, m1 = 0, m2 = 0;                      // m rows s-3,s-2,s-1
    u64 mL0 = 0, mL1 = 0, mL2 = 0, mR0 = 0, mR1 = 0, mR2 = 0;
    u64 cl0 = 0, cl1 = 0;                            // class rows s-2,s-1
    u32 h0 = 0, h1 = 0, h2 = 0, h3 = 0, h4 = 0;      // h rows s-6..s-2
    u32 tq0 = 0, tq1 = 0, tq2 = 0, tq3 = 0, tq4 = 0; // t-bit rows s..s-4
    float accv = 0.0f;

    // pipeline registers: target row for current step, pred row for current emit
    float4 t0, t1, t2, t3;
    {
        int rc = a - 4; rc = rc < 0 ? 0 : rc;
        const float4* tp = (const float4*)(timg + (size_t)rc * W_IMG + cb);
        t0 = tp[0]; t1 = tp[1]; t2 = tp[2]; t3 = tp[3];
    }
    float4 p0 = {0,0,0,0}, p1 = {0,0,0,0}, p2 = {0,0,0,0}, p3 = {0,0,0,0};

    const int send = a + 4 + BH;
    for (int s = a - 4; s < send; ++s) {
        // ---- prefetch (consumed next step) ----
        int rn = s + 1; rn = rn < 0 ? 0 : (rn > H_IMG - 1 ? H_IMG - 1 : rn);
        const float4* tpn = (const float4*)(timg + (size_t)rn * W_IMG + cb);
        float4 n0 = tpn[0], n1 = tpn[1], n2 = tpn[2], n3 = tpn[3];
        int pr = s - 3; pr = pr < a ? a : (pr > a + BH - 1 ? a + BH - 1 : pr);
        const float4* ppn = (const float4*)(pimg + (size_t)pr * W_IMG + cb);
        float4 q0 = ppn[0], q1 = ppn[1], q2 = ppn[2], q3 = ppn[3];

        // ---- binarize current target row (loaded previous step) ----
        iw0 = iw1; iw1 = iw2; iL0 = iL1; iL1 = iL2; iR0 = iR1; iR1 = iR2;
        u64 w = 0;
        w |= (u64)(t0.x > 0.5f) << 0  | (u64)(t0.y > 0.5f) << 4;
        w |= (u64)(t0.z > 0.5f) << 8  | (u64)(t0.w > 0.5f) << 12;
        w |= (u64)(t1.x > 0.5f) << 16 | (u64)(t1.y > 0.5f) << 20;
        w |= (u64)(t1.z > 0.5f) << 24 | (u64)(t1.w > 0.5f) << 28;
        w |= (u64)(t2.x > 0.5f) << 32 | (u64)(t2.y > 0.5f) << 36;
        w |= (u64)(t2.z > 0.5f) << 40 | (u64)(t2.w > 0.5f) << 44;
        w |= (u64)(t3.x > 0.5f) << 48 | (u64)(t3.y > 0.5f) << 52;
        w |= (u64)(t3.z > 0.5f) << 56 | (u64)(t3.w > 0.5f) << 60;
        iw2 = w;
        u64 up = __shfl_up(w, 1);
        u64 dn = __shfl_down(w, 1);
        if (lane == 0)  up = w << 60;                // col -1 := col 0 (clamp)
        if (lane == 63) dn = w >> 60;                // col 1024 := col 1023
        iL2 = (w << 4) | (up >> 60);
        iR2 = (w >> 4) | ((dn & 0xFULL) << 60);
        tq4 = tq3; tq3 = tq2; tq2 = tq1; tq1 = tq0;
        tq0 = foldK1(w & K1);

        // ---- separable SWAR Sobel -> m/class row s-1 (validated body) ----
        u64 Px = iR0 + (iR1 << 1) + iR2;
        u64 Nx = iL0 + (iL1 << 1) + iL2;
        u64 Py = iL2 + (iw2 << 1) + iR2;
        u64 Ny = iL0 + (iw0 << 1) + iR0;
        u64 Dbx = (Px + K8) - Nx;
        u64 Dby = (Py + K8) - Ny;
        u64 mxp = (Dbx >> 3) & K1;
        u64 mfx = (mxp << 4) - mxp;
        u64 ax = ((Dbx & K7) & mfx) | ((((~Dbx) & K7) + K1) & ~mfx);
        u64 myp = (Dby >> 3) & K1;
        u64 mfy = (myp << 4) - myp;
        u64 ay = ((Dby & K7) & mfy) | ((((~Dby) & K7) + K1) & ~mfy);
        u64 mNew = ax + ay;                          // <= 6
        u64 ax0 = ax & K1, ax1b = (ax >> 1) & K1, ax2b = (ax >> 2) & K1;
        u64 ay0 = ay & K1, ay1b = (ay >> 1) & K1, ay2b = (ay >> 2) & K1;
        u64 axnz = ax0 | ax1b | ax2b;
        u64 aynz = ay0 | ay1b | ay2b;
        u64 axe1 = ax0 & ~(ax1b | ax2b);
        u64 aye1 = ay0 & ~(ay1b | ay2b);
        u64 axg3 = ax2b | (ax1b & ax0);
        u64 ayg3 = ay2b | (ay1b & ay0);
        u64 horiz = ((K1 & ~aynz) & axnz) | (aye1 & axg3);
        u64 vert  = ((K1 & ~axnz) & aynz) | (axe1 & ayg3);
        u64 sd = ((mxp & axnz) & (K1 & ~myp)) | ((K1 & ~mxp) & (myp & aynz));

        m0 = m1; m1 = m2; mL0 = mL1; mL1 = mL2; mR0 = mR1; mR1 = mR2;
        cl0 = cl1; cl1 = horiz | (vert << 1) | (sd << 2);
        u64 upm = __shfl_up(mNew, 1);
        u64 dnm = __shfl_down(mNew, 1);
        m2 = mNew;
        mL2 = (mNew << 4) | (upm >> 60);
        mR2 = (mNew >> 4) | ((dnm & 0xFULL) << 60);

        // ---- SWAR NMS row s-2 (validated body) ----
        u64 CC = cl0;
        u64 H8 = (CC & K1) << 3;
        u64 V8 = ((CC >> 1) & K1) << 3;
        u64 S8 = ((CC >> 2) & K1) << 3;
        u64 kH = gt8(m1, mL1) & geq8(m1, mR1);
        u64 kV = gt8(m1, m0)  & geq8(m1, m2);
        u64 kA = gt8(m1, mR0) & geq8(m1, mL2);
        u64 kB = gt8(m1, mL0) & geq8(m1, mR2);
        u64 nHV = K8 & ~(H8 | V8);
        u64 keep = (H8 & kH) | (V8 & kV) | (nHV & S8 & kA) | (nHV & ~S8 & kB);
        u64 nz = ((m1 | (m1 >> 1) | (m1 >> 2)) & K1) << 3;   // m >= 1
        u64 cand = keep & nz;
        int rr = s - 2;
        if (rr < 1 || rr > H_IMG - 2) cand = 0;
        if (lane == 0)  cand &= ~0xFULL;
        if (lane == 63) cand &= ~(0xFULL << 60);
        u32 sNew = foldK1((cand >> 3) & K1);

        // ---- horizontal 5-OR (zero-padded at image edges) ----
        u32 hu = __shfl_up(sNew, 1);
        u32 hd = __shfl_down(sNew, 1);
        if (lane == 0)  hu = 0;
        if (lane == 63) hd = 0;
        u32 hNew = sNew
                 | ((sNew >> 1) | ((hd & 1u) << 15))
                 | ((sNew >> 2) | ((hd & 3u) << 14))
                 | (((sNew << 1) & 0xFFFFu) | (hu >> 15))
                 | (((sNew << 2) & 0xFFFFu) | (hu >> 14));
        h0 = h1; h1 = h2; h2 = h3; h3 = h4; h4 = hNew;

        // ---- emit BCE for row s-4 (pred loaded previous step) ----
        if (s >= a + 4) {
            u32 ez = h0 | h1 | h2 | h3 | h4;         // rows r-2..r+2
            u32 tb = tq4;                            // t bits of row r
            float4 pv[4] = {p0, p1, p2, p3};
#pragma unroll
            for (int kk = 0; kk < 4; ++kk) {
                float ps[4] = {pv[kk].x, pv[kk].y, pv[kk].z, pv[kk].w};
#pragma unroll
                for (int cc = 0; cc < 4; ++cc) {
                    int k = kk * 4 + cc;
                    float p = ps[cc];
                    float xx = ((tb >> k) & 1) ? p : 1.0f - p;
                    float lg = fmaxf(__logf(xx), -100.0f);
                    accv = fmaf(((ez >> k) & 1) ? 5.0f : 1.0f, -lg, accv);
                }
            }
        }

        // rotate pipeline registers
        t0 = n0; t1 = n1; t2 = n2; t3 = n3;
        p0 = q0; p1 = q1; p2 = q2; p3 = q3;
    }

    // wave reduction -> one partial per band (deterministic, atomic-free)
    for (int off = 32; off > 0; off >>= 1)
        accv += __shfl_down(accv, off);
    if (lane == 0) partials[band] = accv;
}

__global__ __launch_bounds__(256)
void finalize_kernel(const float* __restrict__ partials, float* __restrict__ out,
                     int nbands, double invN)
{
    __shared__ double ws[4];
    double s = 0.0;
    for (int i = threadIdx.x; i < nbands; i += 256) s += (double)partials[i];
    for (int off = 32; off > 0; off >>= 1) s += __shfl_down(s, off);
    int wid = threadIdx.x >> 6, lane = threadIdx.x & 63;
    if (lane == 0) ws[wid] = s;
    __syncthreads();
    if (threadIdx.x == 0) out[0] = (float)((ws[0] + ws[1] + ws[2] + ws[3]) * invN);
}

extern "C" void kernel_launch(void* const* d_in, const int* in_sizes, int n_in,
                              void* d_out, int out_size, void* d_ws, size_t ws_size,
                              hipStream_t stream)
{
    (void)n_in; (void)out_size; (void)ws_size;
    const float* pred   = (const float*)d_in[0];
    const float* target = (const float*)d_in[1];
    const int N = in_sizes[0];
    const int B = N >> 20;                            // images (16)

    float* partials = (float*)d_ws;                   // nbands floats, all rewritten
    const int nbands = B * (H_IMG / BH);              // 2048
    const int nblocks = nbands / 4;                   // 4 bands (waves) per block

    edge_loss_kernel<<<nblocks, 256, 0, stream>>>(pred, target, partials);
    finalize_kernel<<<1, 256, 0, stream>>>(partials, (float*)d_out, nbands,
                                           1.0 / (double)N);
}